// Round 13
// baseline (146.663 us; speedup 1.0000x reference)
//
#include <hip/hip_runtime.h>

// Selective scan as a chunked parallel scan over t (R7/R9 verified compute).
// x:(B,d,L) dA/dB:(B,d,L,n) C:(B,n,L) D:(d,) -> y:(B,d,L); B=64 d=384 L=197 n=16.
//
// Round-13: INLINE-ASM register loads. 8x global_load_dwordx4 per chunk into
// named P/Q double buffers -- the compiler cannot collapse the pipeline
// (R9's failure: VGPR=36, ~2 loads in flight). s_waitcnt vmcnt(0) +
// sched_barrier(0) gate each buffer. 16 waves/CU x 8KB in flight = ~128KB/CU
// HW-guaranteed outstanding, register-return path (bypasses LDS-DMA port).
// x staged in LDS so the global stream is pure 16B-aligned dwordx4.

#define B_   64
#define DIN  384
#define L_   197
#define N_   16
#define LN   (L_ * N_)
#define CSTR 20          // padded LDS stride for Cs
#define NCH  12          // full 16-step chunks (t=0..191); tail t=192..196

typedef float f4 __attribute__((ext_vector_type(4)));

template<int CTRL>
__device__ __forceinline__ float dppmov(float src, float oldv) {
    return __int_as_float(__builtin_amdgcn_update_dpp(
        __float_as_int(oldv), __float_as_int(src), CTRL, 0xF, 0xF, false));
}
__device__ __forceinline__ float qsum(float p) {   // sum over 4-lane quad
    p += __int_as_float(__builtin_amdgcn_update_dpp(0, __float_as_int(p), 0xB1, 0xF, 0xF, true));
    p += __int_as_float(__builtin_amdgcn_update_dpp(0, __float_as_int(p), 0x4E, 0xF, 0xF, true));
    return p;
}
__device__ __forceinline__ float bcast12q(float v) {
    // lane <- lane ((l & 0x13) | 0x0C): row's lane 12+q  (BitMode 0x193)
    return __int_as_float(__builtin_amdgcn_ds_swizzle(__float_as_int(v), 0x193));
}

// inline-asm 16B load with immediate offset (bytes)
#define GL4(dst, base, OFF) \
    asm volatile("global_load_dwordx4 %0, %1, off offset:" #OFF \
                 : "=v"(dst) : "v"(base) : "memory")

#define WAITVM0() do { \
    asm volatile("s_waitcnt vmcnt(0)" ::: "memory"); \
    __builtin_amdgcn_sched_barrier(0); \
} while (0)

__global__ __launch_bounds__(256, 4)
void ssm_asml(const float* __restrict__ x, const float* __restrict__ dA,
              const float* __restrict__ dB, const float* __restrict__ C,
              const float* __restrict__ D, float* __restrict__ y)
{
    __shared__ __align__(16) float Cs[L_ * CSTR];   // Cs[t*20+n] = C[b,n,t]
    __shared__ float Xs[16 * L_];                    // Xs[chain*197+t]

    const int tid = threadIdx.x;
    const int b   = blockIdx.y;

    const float* Cg = C + (size_t)b * LN;
    for (int i = tid; i < LN; i += 256) {
        const int n = i / L_;
        const int t = i - n * L_;
        Cs[t * CSTR + n] = Cg[i];
    }
    const float* Xg = x + ((size_t)b * DIN + blockIdx.x * 16) * L_;
    for (int i = tid; i < 16 * L_; i += 256) Xs[i] = Xg[i];
    __syncthreads();

    const int lane = tid & 63;
    const int wav  = tid >> 6;
    const int row  = lane >> 4;        // chain within wave
    const int p    = lane & 15;
    const int p4   = p >> 2;           // t-quad
    const int q    = p & 3;            // n-quad

    const int d   = blockIdx.x * 16 + wav * 4 + row;
    const size_t bd = (size_t)b * DIN + d;

    const float* Arow = dA + bd * (size_t)LN;
    const float* Brow = dB + bd * (size_t)LN;
    float*       Yrow = y  + bd * L_;
    const float  Dd   = D[d];
    const int laneAB  = p4 * 64 + q * 4;
    const float* CsQ  = Cs + q * 4;
    const float* XsL  = Xs + (wav * 4 + row) * L_ + p4 * 4;

    float hcx = 0.f, hcy = 0.f, hcz = 0.f, hcw = 0.f;   // carry h[n=q*4+e]

    f4 PA0,PA1,PA2,PA3, PG0,PG1,PG2,PG3;
    f4 QA0,QA1,QA2,QA3, QG0,QG1,QG2,QG3;

#define LOADC(Pfx, c) do { \
    const float* _a = Arow + (c)*256 + laneAB; \
    const float* _g = Brow + (c)*256 + laneAB; \
    GL4(Pfx##A0, _a, 0);   GL4(Pfx##A1, _a, 64); \
    GL4(Pfx##A2, _a, 128); GL4(Pfx##A3, _a, 192); \
    GL4(Pfx##G0, _g, 0);   GL4(Pfx##G1, _g, 64); \
    GL4(Pfx##G2, _g, 128); GL4(Pfx##G3, _g, 192); \
} while (0)

#define LOADT(Pfx) do { \
    const int _tb = 192 + p4*4; \
    const int _t0 = _tb   > 196 ? 196 : _tb; \
    const int _t1 = _tb+1 > 196 ? 196 : _tb+1; \
    const int _t2 = _tb+2 > 196 ? 196 : _tb+2; \
    const int _t3 = _tb+3 > 196 ? 196 : _tb+3; \
    GL4(Pfx##A0, Arow + _t0*16 + q*4, 0); \
    GL4(Pfx##A1, Arow + _t1*16 + q*4, 0); \
    GL4(Pfx##A2, Arow + _t2*16 + q*4, 0); \
    GL4(Pfx##A3, Arow + _t3*16 + q*4, 0); \
    GL4(Pfx##G0, Brow + _t0*16 + q*4, 0); \
    GL4(Pfx##G1, Brow + _t1*16 + q*4, 0); \
    GL4(Pfx##G2, Brow + _t2*16 + q*4, 0); \
    GL4(Pfx##G3, Brow + _t3*16 + q*4, 0); \
} while (0)

#define SCANE(Pfx, E) do { \
    Pfx##G0.E *= x0; Pfx##G1.E *= x1; Pfx##G2.E *= x2; Pfx##G3.E *= x3; \
    Pfx##G1.E = fmaf(Pfx##A1.E, Pfx##G0.E, Pfx##G1.E); Pfx##A1.E *= Pfx##A0.E; \
    Pfx##G2.E = fmaf(Pfx##A2.E, Pfx##G1.E, Pfx##G2.E); Pfx##A2.E *= Pfx##A1.E; \
    Pfx##G3.E = fmaf(Pfx##A3.E, Pfx##G2.E, Pfx##G3.E); Pfx##A3.E *= Pfx##A2.E; \
    float _ta = Pfx##A3.E, _tv = Pfx##G3.E; \
    { float _pa = dppmov<0x114>(_ta, 1.0f), _pb = dppmov<0x114>(_tv, 0.0f); \
      _tv = fmaf(_ta, _pb, _tv); _ta *= _pa; } \
    { float _pa = dppmov<0x118>(_ta, 1.0f), _pb = dppmov<0x118>(_tv, 0.0f); \
      _tv = fmaf(_ta, _pb, _tv); _ta *= _pa; } \
    const float _Ea = dppmov<0x114>(_ta, 1.0f); \
    const float _Eb = dppmov<0x114>(_tv, 0.0f); \
    const float _s  = fmaf(_Ea, hc##E, _Eb); \
    Pfx##G0.E = fmaf(Pfx##A0.E, _s, Pfx##G0.E); \
    Pfx##G1.E = fmaf(Pfx##A1.E, _s, Pfx##G1.E); \
    Pfx##G2.E = fmaf(Pfx##A2.E, _s, Pfx##G2.E); \
    Pfx##G3.E = fmaf(Pfx##A3.E, _s, Pfx##G3.E); \
} while (0)

#define YJ(Pfx, j, tcj, xv, yf) do { \
    const f4 _c4 = *(const f4*)(CsQ + (tcj)*CSTR); \
    float _yp = fmaf(Pfx##G##j.x, _c4.x, fmaf(Pfx##G##j.y, _c4.y, \
                 fmaf(Pfx##G##j.z, _c4.z, Pfx##G##j.w * _c4.w))); \
    _yp = qsum(_yp); \
    yf = fmaf(xv, Dd, _yp); \
} while (0)

#define COMPUTE(Pfx, c, TAIL) do { \
    const int _t0s = (TAIL) ? (192 + p4*4) : ((c)*16 + p4*4); \
    int _c0 = _t0s, _c1 = _t0s+1, _c2 = _t0s+2, _c3 = _t0s+3; \
    if (TAIL) { _c0 = _c0>196?196:_c0; _c1 = _c1>196?196:_c1; \
                _c2 = _c2>196?196:_c2; _c3 = _c3>196?196:_c3; } \
    const float x0 = (TAIL) ? Xs[(wav*4+row)*L_ + _c0] : XsL[(c)*16 + 0]; \
    const float x1 = (TAIL) ? Xs[(wav*4+row)*L_ + _c1] : XsL[(c)*16 + 1]; \
    const float x2 = (TAIL) ? Xs[(wav*4+row)*L_ + _c2] : XsL[(c)*16 + 2]; \
    const float x3 = (TAIL) ? Xs[(wav*4+row)*L_ + _c3] : XsL[(c)*16 + 3]; \
    SCANE(Pfx, x); SCANE(Pfx, y); SCANE(Pfx, z); SCANE(Pfx, w); \
    float _yf0,_yf1,_yf2,_yf3; \
    YJ(Pfx, 0, _c0, x0, _yf0); YJ(Pfx, 1, _c1, x1, _yf1); \
    YJ(Pfx, 2, _c2, x2, _yf2); YJ(Pfx, 3, _c3, x3, _yf3); \
    hcx = bcast12q(Pfx##G3.x); hcy = bcast12q(Pfx##G3.y); \
    hcz = bcast12q(Pfx##G3.z); hcw = bcast12q(Pfx##G3.w); \
    const float _ys = (q==0) ? _yf0 : (q==1) ? _yf1 : (q==2) ? _yf2 : _yf3; \
    if (!(TAIL) || p4 == 0 || (p4 == 1 && q == 0)) Yrow[_t0s + q] = _ys; \
} while (0)

    LOADC(P, 0);
    WAITVM0();

#pragma unroll 1
    for (int c = 0; c < NCH; c += 2) {
        LOADC(Q, c + 1);          // 8 loads in flight during COMPUTE(P)
        COMPUTE(P, c, 0);
        WAITVM0();                // Q resident (also drains our y-stores)
        if (c + 2 < NCH) { LOADC(P, c + 2); } else { LOADT(P); }
        COMPUTE(Q, c + 1, 0);
        WAITVM0();                // P resident
    }
    COMPUTE(P, 0, 1);             // tail t=192..196

#undef COMPUTE
#undef YJ
#undef SCANE
#undef LOADT
#undef LOADC
}

extern "C" void kernel_launch(void* const* d_in, const int* in_sizes, int n_in,
                              void* d_out, int out_size, void* d_ws, size_t ws_size,
                              hipStream_t stream) {
    const float* x  = (const float*)d_in[0];
    const float* dA = (const float*)d_in[1];
    const float* dB = (const float*)d_in[2];
    const float* C  = (const float*)d_in[3];
    const float* D  = (const float*)d_in[4];
    float* yo = (float*)d_out;

    dim3 grid(DIN / 16, B_);   // (24, 64) = 1536 blocks, 16 chains/block
    dim3 block(256);           // 4 waves; VGPR-capped for 16 waves/CU
    ssm_asml<<<grid, block, 0, stream>>>(x, dA, dB, C, D, yo);
}